// Round 2
// baseline (30196.313 us; speedup 1.0000x reference)
//
#include <hip/hip_runtime.h>
#include <hip/hip_bf16.h>

typedef short short8 __attribute__((ext_vector_type(8)));
typedef float f32x4 __attribute__((ext_vector_type(4)));

static constexpr int T_SEQ = 256;
static constexpr int NB    = 64;
static constexpr int HDIM  = 512;
static constexpr int KIN   = 1024;   // input width of both layers (IN = 2H = 1024)

__device__ __forceinline__ float sigf(float x) { return 1.0f / (1.0f + __expf(-x)); }
__device__ __forceinline__ float tanh_fast(float x) {
  x = fminf(fmaxf(x, -15.0f), 15.0f);
  float e = __expf(2.0f * x);
  return (e - 1.0f) / (e + 1.0f);
}

// ---- fp32 -> bf16 hi + lo split -------------------------------------------
__global__ void split_kernel(const float* __restrict__ src,
                             __hip_bfloat16* __restrict__ hi,
                             __hip_bfloat16* __restrict__ lo, int n) {
  int i = blockIdx.x * blockDim.x + threadIdx.x;
  if (i < n) {
    float v = src[i];
    __hip_bfloat16 h = __float2bfloat16(v);
    hi[i] = h;
    lo[i] = __float2bfloat16(v - __bfloat162float(h));
  }
}

// ---- fused persistent bidirectional 2-layer LSTM ---------------------------
// 256 WGs x 256 thr. bi -> d=bi>>7 (dir), ms=(bi>>5)&3 (16-batch chunk),
// nc=bi&31 (16-j chunk). Group = (d,ms) = bi>>5: 32 WGs share one h stream.
// Wave w = gate g. W_ih slice (16 rows x 1024, hi+lo) and W_hh slice
// (16 rows x 512, hi+lo) live in VGPRs for the whole layer (~384 VGPRs).
__global__ __launch_bounds__(256, 1) void lstm_fused_kernel(
    const __hip_bfloat16* __restrict__ Xhi, const __hip_bfloat16* __restrict__ Xlo,
    __hip_bfloat16* __restrict__ O0hi, __hip_bfloat16* __restrict__ O0lo,
    const __hip_bfloat16* __restrict__ WihHi, const __hip_bfloat16* __restrict__ WihLo,
    const __hip_bfloat16* __restrict__ WhhHi, const __hip_bfloat16* __restrict__ WhhLo,
    const float* __restrict__ b_ih, const float* __restrict__ b_hh,
    const int* __restrict__ mask,
    __hip_bfloat16* __restrict__ Hhi, __hip_bfloat16* __restrict__ Hlo,
    unsigned int* __restrict__ cnt,    // [8 groups * 32] (cacheline-spread), zeroed
    unsigned int* __restrict__ gcnt,   // global barrier counter, zeroed
    float* __restrict__ out)
{
  const int tid = threadIdx.x;
  const int g = tid >> 6, l = tid & 63;
  const int lane15 = l & 15, quad = l >> 4;
  const int bi = blockIdx.x;
  const int d = bi >> 7;
  const int ms = (bi >> 5) & 3;
  const int grp = bi >> 5;
  const int nc = bi & 31;
  const int b0 = ms * 16, j0 = nc * 16;
  const int ub = tid >> 4, uj = tid & 15;
  const int b_u = b0 + ub, j_u = j0 + uj;
  unsigned int* mycnt = cnt + grp * 32;

  __shared__ float Glds[4][16][17];

  unsigned int gen = 0;

  for (int layer = 0; layer < 2; ++layer) {
    // ---- inter-layer global barrier: O0 fully written before layer 1 ----
    if (layer == 1) {
      __threadfence();
      __syncthreads();
      if (tid == 0) {
        __hip_atomic_fetch_add(gcnt, 1u, __ATOMIC_RELEASE, __HIP_MEMORY_SCOPE_AGENT);
        while (__hip_atomic_load(gcnt, __ATOMIC_RELAXED, __HIP_MEMORY_SCOPE_AGENT) < 256u) {}
      }
      __syncthreads();
      __threadfence();
    }

    // ---- preload this wave's weight slices into VGPRs ----
    short8 wih_h[32], wih_l[32], whh_h[16], whh_l[16];
    {
      const size_t rw = (size_t)((layer * 2 + d) * 2048 + g * 512 + j0 + lane15);
      const __hip_bfloat16* pih_h = WihHi + rw * 1024 + quad * 8;
      const __hip_bfloat16* pih_l = WihLo + rw * 1024 + quad * 8;
      const __hip_bfloat16* phh_h = WhhHi + rw * 512 + quad * 8;
      const __hip_bfloat16* phh_l = WhhLo + rw * 512 + quad * 8;
      #pragma unroll
      for (int kk = 0; kk < 32; ++kk) {
        wih_h[kk] = *(const short8*)(pih_h + kk * 32);
        wih_l[kk] = *(const short8*)(pih_l + kk * 32);
      }
      #pragma unroll
      for (int kk = 0; kk < 16; ++kk) {
        whh_h[kk] = *(const short8*)(phh_h + kk * 32);
        whh_l[kk] = *(const short8*)(phh_l + kk * 32);
      }
    }
    // biases for the update-phase cell (b_u, j_u), all 4 gates
    float bias_c[4];
    #pragma unroll
    for (int g2 = 0; g2 < 4; ++g2) {
      int o = (layer * 2 + d) * 2048 + g2 * 512 + j_u;
      bias_c[g2] = b_ih[o] + b_hh[o];
    }
    const __hip_bfloat16* Xh = layer ? O0hi : Xhi;
    const __hip_bfloat16* Xl = layer ? O0lo : Xlo;

    // ---- zero h(buffer 0) + c; publish via group barrier ----
    float c = 0.0f;
    {
      size_t hoff = (((size_t)d * 2 + 0) * 64 + b_u) * 512 + j_u;
      Hhi[hoff] = __float2bfloat16(0.0f);
      Hlo[hoff] = __float2bfloat16(0.0f);
    }
    __threadfence();
    __syncthreads();
    if (tid == 0) __hip_atomic_fetch_add(mycnt, 1u, __ATOMIC_RELEASE, __HIP_MEMORY_SCOPE_AGENT);
    gen++;

    for (int s = 0; s < 256; ++s) {
      const int t = d ? (255 - s) : s;
      const int cur = s & 1, nxt = cur ^ 1;
      float mval = (float)mask[b_u * 256 + t];

      // ---- phase 1: x-projection (independent of h) ----
      f32x4 a0 = {}, a1 = {}, a2 = {};
      const __hip_bfloat16* xh = Xh + (size_t)(t * 64 + b0 + lane15) * 1024 + quad * 8;
      const __hip_bfloat16* xl = Xl + (size_t)(t * 64 + b0 + lane15) * 1024 + quad * 8;
      #pragma unroll
      for (int kk = 0; kk < 32; ++kk) {
        short8 ah = *(const short8*)(xh + kk * 32);
        short8 al = *(const short8*)(xl + kk * 32);
        a0 = __builtin_amdgcn_mfma_f32_16x16x32_bf16(ah, wih_h[kk], a0, 0, 0, 0);
        a1 = __builtin_amdgcn_mfma_f32_16x16x32_bf16(ah, wih_l[kk], a1, 0, 0, 0);
        a2 = __builtin_amdgcn_mfma_f32_16x16x32_bf16(al, wih_h[kk], a2, 0, 0, 0);
      }

      // ---- group barrier: wait for h(cur) from step s-1 ----
      if (tid == 0) {
        const unsigned int tgt = gen * 32u;
        while (__hip_atomic_load(mycnt, __ATOMIC_RELAXED, __HIP_MEMORY_SCOPE_AGENT) < tgt) {}
      }
      __syncthreads();
      __threadfence();  // acquire: invalidate caches before reading h

      // ---- phase 2: recurrent projection ----
      const __hip_bfloat16* hh_p = Hhi + (((size_t)d * 2 + cur) * 64 + b0 + lane15) * 512 + quad * 8;
      const __hip_bfloat16* hl_p = Hlo + (((size_t)d * 2 + cur) * 64 + b0 + lane15) * 512 + quad * 8;
      #pragma unroll
      for (int kk = 0; kk < 16; ++kk) {
        short8 ah = *(const short8*)(hh_p + kk * 32);
        short8 al = *(const short8*)(hl_p + kk * 32);
        a0 = __builtin_amdgcn_mfma_f32_16x16x32_bf16(ah, whh_h[kk], a0, 0, 0, 0);
        a1 = __builtin_amdgcn_mfma_f32_16x16x32_bf16(ah, whh_l[kk], a1, 0, 0, 0);
        a2 = __builtin_amdgcn_mfma_f32_16x16x32_bf16(al, whh_h[kk], a2, 0, 0, 0);
      }
      // D layout: row(b) = quad*4+r, col(j) = lane15
      #pragma unroll
      for (int r = 0; r < 4; ++r)
        Glds[g][quad * 4 + r][lane15] = a0[r] + a1[r] + a2[r];
      __syncthreads();

      // ---- update phase: one (b,j) cell per thread ----
      float gi = Glds[0][ub][uj] + bias_c[0];
      float gf = Glds[1][ub][uj] + bias_c[1];
      float gg = Glds[2][ub][uj] + bias_c[2];
      float go = Glds[3][ub][uj] + bias_c[3];
      float cn = sigf(gf) * c + sigf(gi) * tanh_fast(gg);
      float h  = sigf(go) * tanh_fast(cn);
      h *= mval; cn *= mval;
      c = cn;

      __hip_bfloat16 hh = __float2bfloat16(h);
      __hip_bfloat16 hl = __float2bfloat16(h - __bfloat162float(hh));
      size_t hoff = (((size_t)d * 2 + nxt) * 64 + b_u) * 512 + j_u;
      Hhi[hoff] = hh;
      Hlo[hoff] = hl;
      size_t ooff = (size_t)(t * 64 + b_u) * 1024 + d * 512 + j_u;
      if (layer == 0) { O0hi[ooff] = hh; O0lo[ooff] = hl; }
      else            { out[ooff] = h; }

      __threadfence();   // release h + outputs
      __syncthreads();   // whole WG done before arrive
      if (tid == 0) __hip_atomic_fetch_add(mycnt, 1u, __ATOMIC_RELEASE, __HIP_MEMORY_SCOPE_AGENT);
      gen++;
    }
  }
}

// ---- host ------------------------------------------------------------------
extern "C" void kernel_launch(void* const* d_in, const int* in_sizes, int n_in,
                              void* d_out, int out_size, void* d_ws, size_t ws_size,
                              hipStream_t stream) {
  const float* x    = (const float*)d_in[0];
  const int*   mask = (const int*)  d_in[1];
  const float* w_ih = (const float*)d_in[2];
  const float* w_hh = (const float*)d_in[3];
  const float* b_ih = (const float*)d_in[4];
  const float* b_hh = (const float*)d_in[5];
  float* outp = (float*)d_out;

  char* ws = (char*)d_ws;
  size_t off = 0;
  auto take = [&](size_t bytes) -> char* {
    char* p = ws + off;
    off += (bytes + 255) & ~(size_t)255;
    return p;
  };
  const size_t NX   = (size_t)T_SEQ * NB * KIN;        // 16.7M
  const size_t NWIH = (size_t)2 * 2 * 2048 * 1024;     // 8.39M
  const size_t NWHH = (size_t)2 * 2 * 2048 * 512;      // 4.19M
  const size_t NH   = (size_t)2 * 2 * NB * HDIM;       // 131K

  __hip_bfloat16* Xhi   = (__hip_bfloat16*)take(NX * 2);
  __hip_bfloat16* Xlo   = (__hip_bfloat16*)take(NX * 2);
  __hip_bfloat16* O0hi  = (__hip_bfloat16*)take(NX * 2);
  __hip_bfloat16* O0lo  = (__hip_bfloat16*)take(NX * 2);
  __hip_bfloat16* WihHi = (__hip_bfloat16*)take(NWIH * 2);
  __hip_bfloat16* WihLo = (__hip_bfloat16*)take(NWIH * 2);
  __hip_bfloat16* WhhHi = (__hip_bfloat16*)take(NWHH * 2);
  __hip_bfloat16* WhhLo = (__hip_bfloat16*)take(NWHH * 2);
  __hip_bfloat16* Hhi   = (__hip_bfloat16*)take(NH * 2);
  __hip_bfloat16* Hlo   = (__hip_bfloat16*)take(NH * 2);
  unsigned int*   cnt   = (unsigned int*)  take(4096);   // 8 groups*32 uints + gcnt
  unsigned int*   gcnt  = cnt + 8 * 32;

  hipMemsetAsync(cnt, 0, 4096, stream);

  { int n = (int)NX;   split_kernel<<<(n + 255) / 256, 256, 0, stream>>>(x,    Xhi,   Xlo,   n); }
  { int n = (int)NWIH; split_kernel<<<(n + 255) / 256, 256, 0, stream>>>(w_ih, WihHi, WihLo, n); }
  { int n = (int)NWHH; split_kernel<<<(n + 255) / 256, 256, 0, stream>>>(w_hh, WhhHi, WhhLo, n); }

  lstm_fused_kernel<<<256, 256, 0, stream>>>(
      Xhi, Xlo, O0hi, O0lo, WihHi, WihLo, WhhHi, WhhLo,
      b_ih, b_hh, mask, Hhi, Hlo, cnt, gcnt, outp);
}

// Round 3
// 14933.852 us; speedup vs baseline: 2.0220x; 2.0220x over previous
//
#include <hip/hip_runtime.h>
#include <hip/hip_bf16.h>

typedef short short8 __attribute__((ext_vector_type(8)));
typedef float f32x4 __attribute__((ext_vector_type(4)));

static constexpr int T_SEQ = 256;
static constexpr int NB    = 64;
static constexpr int HDIM  = 512;
static constexpr int KIN   = 1024;

#define MFMA16 __builtin_amdgcn_mfma_f32_16x16x32_bf16

__device__ __forceinline__ float sigf(float x) { return 1.0f / (1.0f + __expf(-x)); }
__device__ __forceinline__ float tanh_fast(float x) {
  x = fminf(fmaxf(x, -15.0f), 15.0f);
  float e = __expf(2.0f * x);
  return (e - 1.0f) / (e + 1.0f);
}
__device__ __forceinline__ unsigned short f2bfu(float v) {
  __hip_bfloat16 b = __float2bfloat16(v);
  unsigned short u; __builtin_memcpy(&u, &b, 2); return u;
}
__device__ __forceinline__ float bfu2f(unsigned short u) {
  __hip_bfloat16 b; __builtin_memcpy(&b, &u, 2); return __bfloat162float(b);
}
__device__ __forceinline__ __hip_bfloat16 u2bf(unsigned short u) {
  __hip_bfloat16 b; __builtin_memcpy(&b, &u, 2); return b;
}

// ---- fp32 -> bf16 hi + lo split -------------------------------------------
__global__ void split_kernel(const float* __restrict__ src,
                             __hip_bfloat16* __restrict__ hi,
                             __hip_bfloat16* __restrict__ lo, int n) {
  int i = blockIdx.x * blockDim.x + threadIdx.x;
  if (i < n) {
    float v = src[i];
    __hip_bfloat16 h = __float2bfloat16(v);
    hi[i] = h;
    lo[i] = __float2bfloat16(v - __bfloat162float(h));
  }
}

// ---- fused persistent bidirectional 2-layer LSTM ---------------------------
// 256 WGs x 256 thr; 1 WG/CU. bi -> d (dir), ms (16-batch chunk), nc (16-j chunk).
// Group (d,ms) = 32 WGs sharing one h stream. Wave w covers 4 j-cols x all 4
// gates (B n-index = gate*4 + jn), so the gate combine is intra-wave shfl —
// no per-step __syncthreads. h passes through agent-scope cache-bypass
// loads/stores (packed bf16 hi|lo per uint32); no threadfence in the loop.
__global__ __launch_bounds__(256, 1) void lstm_fused_kernel(
    const __hip_bfloat16* __restrict__ Xhi, const __hip_bfloat16* __restrict__ Xlo,
    __hip_bfloat16* __restrict__ O0hi, __hip_bfloat16* __restrict__ O0lo,
    const __hip_bfloat16* __restrict__ WihHi, const __hip_bfloat16* __restrict__ WihLo,
    const __hip_bfloat16* __restrict__ WhhHi, const __hip_bfloat16* __restrict__ WhhLo,
    const float* __restrict__ b_ih, const float* __restrict__ b_hh,
    const int* __restrict__ mask,
    unsigned int* __restrict__ Hpk,   // [2 dirs][2 slots][64][512] packed hi|lo
    unsigned int* __restrict__ cnt,   // per-group counters, 64-uint spaced, zeroed
    unsigned int* __restrict__ gcnt,  // layer barrier counter, zeroed
    float* __restrict__ out)
{
  const int tid = threadIdx.x;
  const int w = tid >> 6, l = tid & 63;
  const int lane15 = l & 15, quad = l >> 4;
  const int gn = lane15 >> 2, jn = lane15 & 3;   // gate / j-sub for B-operand col
  const int bi = blockIdx.x;
  const int d = bi >> 7, ms = (bi >> 5) & 3, grp = bi >> 5, nc = bi & 31;
  const int b0 = ms * 16, j0 = nc * 16;
  const int jcol = j0 + w * 4 + jn;              // this lane's j column
  unsigned int* mycnt = cnt + grp * 64;

  __shared__ unsigned int ldsCnt;
  if (tid == 0) ldsCnt = 0;
  __syncthreads();

  unsigned int gen = 0;

  for (int layer = 0; layer < 2; ++layer) {
    // ---- one-time inter-layer barrier (O0 plain cached stores -> flush/inv) ----
    if (layer == 1) {
      __builtin_amdgcn_s_waitcnt(0);   // each wave drains its own stores into L2
      __syncthreads();
      if (tid == 0) {
        __threadfence();               // release: wbl2 this XCD's L2
        __hip_atomic_fetch_add(gcnt, 1u, __ATOMIC_RELAXED, __HIP_MEMORY_SCOPE_AGENT);
        while (__hip_atomic_load(gcnt, __ATOMIC_RELAXED, __HIP_MEMORY_SCOPE_AGENT) < 256u)
          __builtin_amdgcn_s_sleep(1);
      }
      __syncthreads();
      __threadfence();                 // acquire by every wave: invalidate stale lines
    }

    // ---- weight fragments: wih_h, whh_h, whh_l register-resident ----
    const size_t rw = (size_t)((layer * 2 + d) * 2048 + gn * 512 + jcol);
    const __hip_bfloat16* pih_h = WihHi + rw * 1024 + quad * 8;
    const __hip_bfloat16* pih_l = WihLo + rw * 1024 + quad * 8;  // streamed from L2 per step
    const __hip_bfloat16* phh_h = WhhHi + rw * 512 + quad * 8;
    const __hip_bfloat16* phh_l = WhhLo + rw * 512 + quad * 8;
    short8 wih_h[32], whh_h[16], whh_l[16];
    #pragma unroll
    for (int kk = 0; kk < 32; ++kk) wih_h[kk] = *(const short8*)(pih_h + kk * 32);
    #pragma unroll
    for (int kk = 0; kk < 16; ++kk) {
      whh_h[kk] = *(const short8*)(phh_h + kk * 32);
      whh_l[kk] = *(const short8*)(phh_l + kk * 32);
    }
    // biases for this lane's j column, all 4 gates
    float bias_c[4];
    #pragma unroll
    for (int g2 = 0; g2 < 4; ++g2) {
      int o = (layer * 2 + d) * 2048 + g2 * 512 + jcol;
      bias_c[g2] = b_ih[o] + b_hh[o];
    }
    const __hip_bfloat16* Xh = layer ? O0hi : Xhi;
    const __hip_bfloat16* Xl = layer ? O0lo : Xlo;

    f32x4 c4 = {0.f, 0.f, 0.f, 0.f};

    // ---- publish h(t=init) = 0 into slot 0 ----
    if (gn == 0) {
      #pragma unroll
      for (int r = 0; r < 4; ++r) {
        size_t ho = (((size_t)d * 2 + 0) * 64 + b0 + quad * 4 + r) * 512 + jcol;
        __hip_atomic_store(Hpk + ho, 0u, __ATOMIC_RELAXED, __HIP_MEMORY_SCOPE_AGENT);
      }
    }
    __builtin_amdgcn_s_waitcnt(0);
    if (l == 0) {
      unsigned int old = atomicAdd(&ldsCnt, 1u);
      if ((old & 3u) == 3u)
        __hip_atomic_fetch_add(mycnt, 1u, __ATOMIC_RELAXED, __HIP_MEMORY_SCOPE_AGENT);
    }
    gen++;

    for (int s = 0; s < 256; ++s) {
      const int t = d ? (255 - s) : s;
      const int cur = s & 1, nxt = cur ^ 1;

      float mv[4];
      #pragma unroll
      for (int r = 0; r < 4; ++r) mv[r] = (float)mask[(b0 + quad * 4 + r) * 256 + t];

      // ---- x-projection (independent of h; overlaps group progress) ----
      f32x4 a0 = {}, a1 = {}, a2 = {};
      const __hip_bfloat16* xh = Xh + (size_t)(t * 64 + b0 + lane15) * 1024 + quad * 8;
      const __hip_bfloat16* xl = Xl + (size_t)(t * 64 + b0 + lane15) * 1024 + quad * 8;
      #pragma unroll
      for (int kk = 0; kk < 32; ++kk) {
        short8 ah = *(const short8*)(xh + kk * 32);
        short8 al = *(const short8*)(xl + kk * 32);
        a0 = MFMA16(ah, wih_h[kk], a0, 0, 0, 0);
        a1 = MFMA16(ah, *(const short8*)(pih_l + kk * 32), a1, 0, 0, 0);
        a2 = MFMA16(al, wih_h[kk], a2, 0, 0, 0);
      }

      // ---- wait for h(cur): per-wave spin, no syncthreads, no fence ----
      if (l == 0) {
        const unsigned int tgt = gen * 32u;
        while (__hip_atomic_load(mycnt, __ATOMIC_RELAXED, __HIP_MEMORY_SCOPE_AGENT) < tgt)
          __builtin_amdgcn_s_sleep(1);
      }
      __atomic_signal_fence(__ATOMIC_ACQUIRE);

      // ---- recurrent projection: h via cache-bypass dword loads ----
      const unsigned int* hp = Hpk + (((size_t)d * 2 + cur) * 64 + b0 + lane15) * 512 + quad * 8;
      #pragma unroll
      for (int kk = 0; kk < 16; ++kk) {
        unsigned int v[8];
        #pragma unroll
        for (int e = 0; e < 8; ++e)
          v[e] = __hip_atomic_load(hp + kk * 32 + e, __ATOMIC_RELAXED, __HIP_MEMORY_SCOPE_AGENT);
        short8 ah, al;
        #pragma unroll
        for (int e = 0; e < 8; ++e) { ah[e] = (short)(v[e] & 0xffffu); al[e] = (short)(v[e] >> 16); }
        a0 = MFMA16(ah, whh_h[kk], a0, 0, 0, 0);
        a1 = MFMA16(ah, whh_l[kk], a1, 0, 0, 0);
        a2 = MFMA16(al, whh_h[kk], a2, 0, 0, 0);
      }
      f32x4 gsum = a0 + a1 + a2;   // lane: gate gn, col jcol, rows b0+quad*4+r

      // ---- gather all 4 gates intra-wave (lane15^4 flips gate bit0, ^8 bit1) ----
      f32x4 p1, p2, p3;
      #pragma unroll
      for (int e = 0; e < 4; ++e) {
        p1[e] = __shfl_xor(gsum[e], 4);
        p2[e] = __shfl_xor(gsum[e], 8);
        p3[e] = __shfl_xor(gsum[e], 12);
      }
      f32x4 Gi = (gn == 0) ? gsum : (gn == 1) ? p1 : (gn == 2) ? p2 : p3;
      f32x4 Gf = (gn == 0) ? p1 : (gn == 1) ? gsum : (gn == 2) ? p3 : p2;
      f32x4 Gg = (gn == 0) ? p2 : (gn == 1) ? p3 : (gn == 2) ? gsum : p1;
      f32x4 Go = (gn == 0) ? p3 : (gn == 1) ? p2 : (gn == 2) ? p1 : gsum;

      float hval[4];
      #pragma unroll
      for (int r = 0; r < 4; ++r) {
        float gi = Gi[r] + bias_c[0];
        float gf = Gf[r] + bias_c[1];
        float gg = Gg[r] + bias_c[2];
        float go = Go[r] + bias_c[3];
        float cn = sigf(gf) * c4[r] + sigf(gi) * tanh_fast(gg);
        float h  = sigf(go) * tanh_fast(cn);
        h *= mv[r]; cn *= mv[r];
        c4[r] = cn;
        hval[r] = h;
      }

      // ---- publish h(nxt) + outputs (gn==0 lanes carry the canonical copy) ----
      if (gn == 0) {
        #pragma unroll
        for (int r = 0; r < 4; ++r) {
          unsigned short uh = f2bfu(hval[r]);
          unsigned short ul = f2bfu(hval[r] - bfu2f(uh));
          unsigned int pk = (unsigned int)uh | ((unsigned int)ul << 16);
          size_t ho = (((size_t)d * 2 + nxt) * 64 + b0 + quad * 4 + r) * 512 + jcol;
          __hip_atomic_store(Hpk + ho, pk, __ATOMIC_RELAXED, __HIP_MEMORY_SCOPE_AGENT);
          size_t oo = (size_t)(t * 64 + b0 + quad * 4 + r) * 1024 + d * 512 + jcol;
          if (layer == 0) { O0hi[oo] = u2bf(uh); O0lo[oo] = u2bf(ul); }
          else            { out[oo] = hval[r]; }
        }
      }
      __atomic_signal_fence(__ATOMIC_RELEASE);
      __builtin_amdgcn_s_waitcnt(0);   // h stores globally visible before arrive
      if (l == 0) {
        unsigned int old = atomicAdd(&ldsCnt, 1u);
        if ((old & 3u) == 3u)
          __hip_atomic_fetch_add(mycnt, 1u, __ATOMIC_RELAXED, __HIP_MEMORY_SCOPE_AGENT);
      }
      gen++;
    }
  }
}

// ---- host ------------------------------------------------------------------
extern "C" void kernel_launch(void* const* d_in, const int* in_sizes, int n_in,
                              void* d_out, int out_size, void* d_ws, size_t ws_size,
                              hipStream_t stream) {
  const float* x    = (const float*)d_in[0];
  const int*   mask = (const int*)  d_in[1];
  const float* w_ih = (const float*)d_in[2];
  const float* w_hh = (const float*)d_in[3];
  const float* b_ih = (const float*)d_in[4];
  const float* b_hh = (const float*)d_in[5];
  float* outp = (float*)d_out;

  char* ws = (char*)d_ws;
  size_t off = 0;
  auto take = [&](size_t bytes) -> char* {
    char* p = ws + off;
    off += (bytes + 255) & ~(size_t)255;
    return p;
  };
  const size_t NX   = (size_t)T_SEQ * NB * KIN;
  const size_t NWIH = (size_t)2 * 2 * 2048 * 1024;
  const size_t NWHH = (size_t)2 * 2 * 2048 * 512;
  const size_t NHP  = (size_t)2 * 2 * NB * HDIM;

  __hip_bfloat16* Xhi   = (__hip_bfloat16*)take(NX * 2);
  __hip_bfloat16* Xlo   = (__hip_bfloat16*)take(NX * 2);
  __hip_bfloat16* O0hi  = (__hip_bfloat16*)take(NX * 2);
  __hip_bfloat16* O0lo  = (__hip_bfloat16*)take(NX * 2);
  __hip_bfloat16* WihHi = (__hip_bfloat16*)take(NWIH * 2);
  __hip_bfloat16* WihLo = (__hip_bfloat16*)take(NWIH * 2);
  __hip_bfloat16* WhhHi = (__hip_bfloat16*)take(NWHH * 2);
  __hip_bfloat16* WhhLo = (__hip_bfloat16*)take(NWHH * 2);
  unsigned int*   Hpk   = (unsigned int*)  take(NHP * 4);
  unsigned int*   cnt   = (unsigned int*)  take(4096);
  unsigned int*   gcnt  = cnt + 8 * 64;

  hipMemsetAsync(cnt, 0, 4096, stream);

  { int n = (int)NX;   split_kernel<<<(n + 255) / 256, 256, 0, stream>>>(x,    Xhi,   Xlo,   n); }
  { int n = (int)NWIH; split_kernel<<<(n + 255) / 256, 256, 0, stream>>>(w_ih, WihHi, WihLo, n); }
  { int n = (int)NWHH; split_kernel<<<(n + 255) / 256, 256, 0, stream>>>(w_hh, WhhHi, WhhLo, n); }

  lstm_fused_kernel<<<256, 256, 0, stream>>>(
      Xhi, Xlo, O0hi, O0lo, WihHi, WihLo, WhhHi, WhhLo,
      b_ih, b_hh, mask, Hpk, cnt, gcnt, outp);
}

// Round 4
// 10407.250 us; speedup vs baseline: 2.9015x; 1.4349x over previous
//
#include <hip/hip_runtime.h>
#include <hip/hip_bf16.h>

typedef short short8 __attribute__((ext_vector_type(8)));
typedef float f32x4 __attribute__((ext_vector_type(4)));
typedef unsigned int uint;
typedef unsigned long long u64;

static constexpr int T_SEQ = 256;
static constexpr int NB    = 64;
static constexpr int HDIM  = 512;
static constexpr int KIN   = 1024;

#define MFMA16 __builtin_amdgcn_mfma_f32_16x16x32_bf16

__device__ __forceinline__ float sigf(float x) { return 1.0f / (1.0f + __expf(-x)); }
__device__ __forceinline__ float tanh_fast(float x) {
  x = fminf(fmaxf(x, -15.0f), 15.0f);
  float e = __expf(2.0f * x);
  return (e - 1.0f) / (e + 1.0f);
}
__device__ __forceinline__ unsigned short f2bfu(float v) {
  __hip_bfloat16 b = __float2bfloat16(v);
  unsigned short u; __builtin_memcpy(&u, &b, 2); return u;
}
__device__ __forceinline__ float bfu2f(unsigned short u) {
  __hip_bfloat16 b; __builtin_memcpy(&b, &u, 2); return __bfloat162float(b);
}

// ---- fp32 -> packed bf16 (hi | lo<<16) dword ------------------------------
__global__ void split_pack_kernel(const float* __restrict__ src,
                                  uint* __restrict__ pk, int n) {
  int i = blockIdx.x * blockDim.x + threadIdx.x;
  if (i < n) {
    float v = src[i];
    unsigned short h = f2bfu(v);
    unsigned short l = f2bfu(v - bfu2f(h));
    pk[i] = (uint)h | ((uint)l << 16);
  }
}

// ---- fp32 -> separate bf16 hi / lo arrays (for 16B B-fragment loads) ------
__global__ void split_kernel(const float* __restrict__ src,
                             __hip_bfloat16* __restrict__ hi,
                             __hip_bfloat16* __restrict__ lo, int n) {
  int i = blockIdx.x * blockDim.x + threadIdx.x;
  if (i < n) {
    float v = src[i];
    __hip_bfloat16 h = __float2bfloat16(v);
    hi[i] = h;
    lo[i] = __float2bfloat16(v - __bfloat162float(h));
  }
}

// ---- fused persistent bidirectional 2-layer LSTM ---------------------------
// 256 WGs x 256 thr, 1 WG/CU. grp = bi & 7 (maps all 32 WGs of a group to one
// XCD under round-robin dispatch - perf heuristic only), nc = bi >> 3.
// Sync per step: distributed tag mailboxes (1 tag line per producer WG, no
// atomic RMW in the loop); wave 0 vector-polls 32 tags, waves 1-3 wait at a
// raw s_barrier. h passes as packed bf16 hi|lo dwords via agent-scope
// cache-bypass (LLC-coherent regardless of WG placement).
__global__ __launch_bounds__(256, 1) void lstm_fused_kernel(
    const uint* __restrict__ Xpk,              // [T*64][1024] packed x (layer 0)
    uint* __restrict__ O0pk,                   // [T*64][1024] packed layer-0 out
    const __hip_bfloat16* __restrict__ WihHi, const __hip_bfloat16* __restrict__ WihLo,
    const __hip_bfloat16* __restrict__ WhhHi, const __hip_bfloat16* __restrict__ WhhLo,
    const float* __restrict__ b_ih, const float* __restrict__ b_hh,
    const int* __restrict__ mask,
    uint* __restrict__ Hpk,                    // [2 dirs][2 slots][64][512] packed
    uint* __restrict__ tags,                   // [8 grp][32 WG] spaced 32 dwords
    uint* __restrict__ gcnt,                   // layer rendezvous counter
    float* __restrict__ out)
{
  const int tid = threadIdx.x;
  const int w = tid >> 6, l = tid & 63;
  const int lane15 = l & 15, quad = l >> 4;
  const int gn = lane15 >> 2, jn = lane15 & 3;
  const int bi = blockIdx.x;
  const int grp = bi & 7, nc = bi >> 3;
  const int d = grp >> 2, ms = grp & 3;
  const int b0 = ms * 16, j0 = nc * 16;
  const int jcol = j0 + w * 4 + jn;
  uint* mytag = tags + grp * 1024 + nc * 32;
  const uint* grptags = tags + grp * 1024;

  uint gen = 0;

  for (int layer = 0; layer < 2; ++layer) {
    // ---- one-time inter-layer rendezvous (no cache flush needed: all ----
    // ---- cross-WG data goes through LLC-bypass stores)               ----
    if (layer == 1) {
      __builtin_amdgcn_s_waitcnt(0);
      __syncthreads();
      if (tid == 0) {
        __hip_atomic_fetch_add(gcnt, 1u, __ATOMIC_RELAXED, __HIP_MEMORY_SCOPE_AGENT);
        while (__hip_atomic_load(gcnt, __ATOMIC_RELAXED, __HIP_MEMORY_SCOPE_AGENT) < 256u)
          __builtin_amdgcn_s_sleep(4);
      }
      __syncthreads();
    }

    // ---- weight fragments: wih_h, whh_h, whh_l register-resident ----
    const size_t rw = (size_t)((layer * 2 + d) * 2048 + gn * 512 + jcol);
    const __hip_bfloat16* pih_h = WihHi + rw * 1024 + quad * 8;
    const __hip_bfloat16* pih_l = WihLo + rw * 1024 + quad * 8;  // streamed (L2)
    const __hip_bfloat16* phh_h = WhhHi + rw * 512 + quad * 8;
    const __hip_bfloat16* phh_l = WhhLo + rw * 512 + quad * 8;
    short8 wih_h[32], whh_h[16], whh_l[16];
    #pragma unroll
    for (int kk = 0; kk < 32; ++kk) wih_h[kk] = *(const short8*)(pih_h + kk * 32);
    #pragma unroll
    for (int kk = 0; kk < 16; ++kk) {
      whh_h[kk] = *(const short8*)(phh_h + kk * 32);
      whh_l[kk] = *(const short8*)(phh_l + kk * 32);
    }
    float bias_c[4];
    #pragma unroll
    for (int g2 = 0; g2 < 4; ++g2) {
      int o = (layer * 2 + d) * 2048 + g2 * 512 + jcol;
      bias_c[g2] = b_ih[o] + b_hh[o];
    }
    const uint* Xp = layer ? O0pk : Xpk;   // layer-1 O0pk lines exist only at
                                           // LLC -> plain cached loads are safe

    f32x4 c4 = {0.f, 0.f, 0.f, 0.f};

    // ---- init publish: h(slot 0) = 0, then tag ----
    if (gn == 0) {
      #pragma unroll
      for (int r = 0; r < 4; ++r) {
        size_t ho = (((size_t)d * 2 + 0) * 64 + b0 + quad * 4 + r) * 512 + jcol;
        __hip_atomic_store(Hpk + ho, 0u, __ATOMIC_RELAXED, __HIP_MEMORY_SCOPE_AGENT);
      }
    }
    __builtin_amdgcn_s_waitcnt(0);
    __builtin_amdgcn_s_barrier();
    gen++;
    if (w == 0 && l == 0)
      __hip_atomic_store(mytag, gen, __ATOMIC_RELAXED, __HIP_MEMORY_SCOPE_AGENT);

    for (int s = 0; s < 256; ++s) {
      const int t = d ? (255 - s) : s;
      const int cur = s & 1, nxt = cur ^ 1;

      float mv[4];
      #pragma unroll
      for (int r = 0; r < 4; ++r) mv[r] = (float)mask[(b0 + quad * 4 + r) * 256 + t];

      // ---- x-projection (independent of h; overlaps peers' publishes) ----
      f32x4 a0 = {}, a1 = {}, a2 = {};
      const uint* xp = Xp + (size_t)(t * 64 + b0 + lane15) * 1024 + quad * 8;
      #pragma unroll
      for (int kk = 0; kk < 32; ++kk) {
        uint v[8];
        *(uint4*)&v[0] = *(const uint4*)(xp + kk * 32);
        *(uint4*)&v[4] = *(const uint4*)(xp + kk * 32 + 4);
        short8 ah, al;
        #pragma unroll
        for (int e = 0; e < 8; ++e) { ah[e] = (short)(v[e] & 0xffffu); al[e] = (short)(v[e] >> 16); }
        a0 = MFMA16(ah, wih_h[kk], a0, 0, 0, 0);
        a1 = MFMA16(ah, *(const short8*)(pih_l + kk * 32), a1, 0, 0, 0);
        a2 = MFMA16(al, wih_h[kk], a2, 0, 0, 0);
      }

      // ---- wait for h(cur): wave 0 polls 32 distributed tags ----
      if (w == 0) {
        for (;;) {
          uint v = 0xffffffffu;
          if (l < 32)
            v = __hip_atomic_load(grptags + l * 32, __ATOMIC_RELAXED, __HIP_MEMORY_SCOPE_AGENT);
          if (__all((int)(v >= gen))) break;
          __builtin_amdgcn_s_sleep(2);
        }
      }
      __atomic_signal_fence(__ATOMIC_ACQUIRE);
      __builtin_amdgcn_s_barrier();
      __atomic_signal_fence(__ATOMIC_ACQUIRE);

      // ---- recurrent projection: h via u64 cache-bypass loads ----
      const u64* hp = (const u64*)(Hpk + (((size_t)d * 2 + cur) * 64 + b0 + lane15) * 512 + quad * 8);
      #pragma unroll
      for (int kk = 0; kk < 16; ++kk) {
        u64 p0 = __hip_atomic_load(hp + kk * 16 + 0, __ATOMIC_RELAXED, __HIP_MEMORY_SCOPE_AGENT);
        u64 p1 = __hip_atomic_load(hp + kk * 16 + 1, __ATOMIC_RELAXED, __HIP_MEMORY_SCOPE_AGENT);
        u64 p2 = __hip_atomic_load(hp + kk * 16 + 2, __ATOMIC_RELAXED, __HIP_MEMORY_SCOPE_AGENT);
        u64 p3 = __hip_atomic_load(hp + kk * 16 + 3, __ATOMIC_RELAXED, __HIP_MEMORY_SCOPE_AGENT);
        uint v[8];
        v[0] = (uint)p0; v[1] = (uint)(p0 >> 32); v[2] = (uint)p1; v[3] = (uint)(p1 >> 32);
        v[4] = (uint)p2; v[5] = (uint)(p2 >> 32); v[6] = (uint)p3; v[7] = (uint)(p3 >> 32);
        short8 ah, al;
        #pragma unroll
        for (int e = 0; e < 8; ++e) { ah[e] = (short)(v[e] & 0xffffu); al[e] = (short)(v[e] >> 16); }
        a0 = MFMA16(ah, whh_h[kk], a0, 0, 0, 0);
        a1 = MFMA16(ah, whh_l[kk], a1, 0, 0, 0);
        a2 = MFMA16(al, whh_h[kk], a2, 0, 0, 0);
      }
      f32x4 gsum = a0 + a1 + a2;

      // ---- gather 4 gates intra-wave (lane15^4 / ^8 flip gate bits) ----
      f32x4 p1v, p2v, p3v;
      #pragma unroll
      for (int e = 0; e < 4; ++e) {
        p1v[e] = __shfl_xor(gsum[e], 4);
        p2v[e] = __shfl_xor(gsum[e], 8);
        p3v[e] = __shfl_xor(gsum[e], 12);
      }
      f32x4 Gi = (gn == 0) ? gsum : (gn == 1) ? p1v : (gn == 2) ? p2v : p3v;
      f32x4 Gf = (gn == 0) ? p1v : (gn == 1) ? gsum : (gn == 2) ? p3v : p2v;
      f32x4 Gg = (gn == 0) ? p2v : (gn == 1) ? p3v : (gn == 2) ? gsum : p1v;
      f32x4 Go = (gn == 0) ? p3v : (gn == 1) ? p2v : (gn == 2) ? p1v : gsum;

      float hval[4];
      #pragma unroll
      for (int r = 0; r < 4; ++r) {
        float gi = Gi[r] + bias_c[0];
        float gf = Gf[r] + bias_c[1];
        float gg = Gg[r] + bias_c[2];
        float go = Go[r] + bias_c[3];
        float cn = sigf(gf) * c4[r] + sigf(gi) * tanh_fast(gg);
        float h  = sigf(go) * tanh_fast(cn);
        h *= mv[r]; cn *= mv[r];
        c4[r] = cn;
        hval[r] = h;
      }

      // ---- publish h(nxt) + layer outputs ----
      if (gn == 0) {
        #pragma unroll
        for (int r = 0; r < 4; ++r) {
          unsigned short uh = f2bfu(hval[r]);
          unsigned short ul = f2bfu(hval[r] - bfu2f(uh));
          uint pk = (uint)uh | ((uint)ul << 16);
          size_t ho = (((size_t)d * 2 + nxt) * 64 + b0 + quad * 4 + r) * 512 + jcol;
          __hip_atomic_store(Hpk + ho, pk, __ATOMIC_RELAXED, __HIP_MEMORY_SCOPE_AGENT);
          size_t oo = (size_t)(t * 64 + b0 + quad * 4 + r) * 1024 + d * 512 + jcol;
          if (layer == 0)
            __hip_atomic_store(O0pk + oo, pk, __ATOMIC_RELAXED, __HIP_MEMORY_SCOPE_AGENT);
          else
            out[oo] = hval[r];
        }
      }
      __atomic_signal_fence(__ATOMIC_RELEASE);
      __builtin_amdgcn_s_waitcnt(0);      // own publishes ACKed at LLC
      __builtin_amdgcn_s_barrier();       // all 4 waves of this WG drained
      gen++;
      if (w == 0 && l == 0)
        __hip_atomic_store(mytag, gen, __ATOMIC_RELAXED, __HIP_MEMORY_SCOPE_AGENT);
    }
  }
}

// ---- host ------------------------------------------------------------------
extern "C" void kernel_launch(void* const* d_in, const int* in_sizes, int n_in,
                              void* d_out, int out_size, void* d_ws, size_t ws_size,
                              hipStream_t stream) {
  const float* x    = (const float*)d_in[0];
  const int*   mask = (const int*)  d_in[1];
  const float* w_ih = (const float*)d_in[2];
  const float* w_hh = (const float*)d_in[3];
  const float* b_ih = (const float*)d_in[4];
  const float* b_hh = (const float*)d_in[5];
  float* outp = (float*)d_out;

  char* ws = (char*)d_ws;
  size_t off = 0;
  auto take = [&](size_t bytes) -> char* {
    char* p = ws + off;
    off += (bytes + 255) & ~(size_t)255;
    return p;
  };
  const size_t NX   = (size_t)T_SEQ * NB * KIN;      // 16.7M elems
  const size_t NWIH = (size_t)2 * 2 * 2048 * 1024;
  const size_t NWHH = (size_t)2 * 2 * 2048 * 512;
  const size_t NHP  = (size_t)2 * 2 * NB * HDIM;

  uint*           Xpk   = (uint*)          take(NX * 4);     // 67 MB
  uint*           O0pk  = (uint*)          take(NX * 4);     // 67 MB
  __hip_bfloat16* WihHi = (__hip_bfloat16*)take(NWIH * 2);
  __hip_bfloat16* WihLo = (__hip_bfloat16*)take(NWIH * 2);
  __hip_bfloat16* WhhHi = (__hip_bfloat16*)take(NWHH * 2);
  __hip_bfloat16* WhhLo = (__hip_bfloat16*)take(NWHH * 2);
  uint*           Hpk   = (uint*)          take(NHP * 4);
  uint*           tags  = (uint*)          take(8 * 1024 * 4);  // 8 grp * 32 WG * 32-dword spacing
  uint*           gcnt  = (uint*)          take(256);

  hipMemsetAsync(tags, 0, 8 * 1024 * 4, stream);
  hipMemsetAsync(gcnt, 0, 256, stream);

  { int n = (int)NX;   split_pack_kernel<<<(n + 255) / 256, 256, 0, stream>>>(x, Xpk, n); }
  { int n = (int)NWIH; split_kernel<<<(n + 255) / 256, 256, 0, stream>>>(w_ih, WihHi, WihLo, n); }
  { int n = (int)NWHH; split_kernel<<<(n + 255) / 256, 256, 0, stream>>>(w_hh, WhhHi, WhhLo, n); }

  lstm_fused_kernel<<<256, 256, 0, stream>>>(
      Xpk, O0pk, WihHi, WihLo, WhhHi, WhhLo,
      b_ih, b_hh, mask, Hpk, tags, gcnt, outp);
}

// Round 5
// 4566.531 us; speedup vs baseline: 6.6125x; 2.2790x over previous
//
#include <hip/hip_runtime.h>
#include <hip/hip_bf16.h>

typedef short short8 __attribute__((ext_vector_type(8)));
typedef _Float16 half8 __attribute__((ext_vector_type(8)));
typedef float f32x4 __attribute__((ext_vector_type(4)));
typedef unsigned int uint;
typedef unsigned short ushort;
typedef unsigned long long u64;

static constexpr int T_SEQ = 256;
static constexpr int NB    = 64;
static constexpr int HDIM  = 512;
static constexpr int KIN   = 1024;

#define MFMA_BF16 __builtin_amdgcn_mfma_f32_16x16x32_bf16
#define MFMA_F16  __builtin_amdgcn_mfma_f32_16x16x32_f16

__device__ __forceinline__ float sigf(float x) { return 1.0f / (1.0f + __expf(-x)); }
__device__ __forceinline__ float tanh_fast(float x) {
  x = fminf(fmaxf(x, -15.0f), 15.0f);
  float e = __expf(2.0f * x);
  return (e - 1.0f) / (e + 1.0f);
}
__device__ __forceinline__ ushort f2bfu(float v) {
  __hip_bfloat16 b = __float2bfloat16(v);
  ushort u; __builtin_memcpy(&u, &b, 2); return u;
}
__device__ __forceinline__ float bfu2f(ushort u) {
  __hip_bfloat16 b; __builtin_memcpy(&b, &u, 2); return __bfloat162float(b);
}
__device__ __forceinline__ ushort f2h16u(float v) {
  _Float16 h = (_Float16)v;
  ushort u; __builtin_memcpy(&u, &h, 2); return u;
}

// ---- fp32 -> fp16 (ushort bits) -------------------------------------------
__global__ void conv_f16_kernel(const float* __restrict__ src,
                                ushort* __restrict__ dst, int n) {
  int i = blockIdx.x * blockDim.x + threadIdx.x;
  if (i < n) dst[i] = f2h16u(src[i]);
}

// ---- fp32 -> bf16 hi + lo split (for W_hh 3-term path) --------------------
__global__ void split_kernel(const float* __restrict__ src,
                             __hip_bfloat16* __restrict__ hi,
                             __hip_bfloat16* __restrict__ lo, int n) {
  int i = blockIdx.x * blockDim.x + threadIdx.x;
  if (i < n) {
    float v = src[i];
    __hip_bfloat16 h = __float2bfloat16(v);
    hi[i] = h;
    lo[i] = __float2bfloat16(v - __bfloat162float(h));
  }
}

// ---- fused persistent bidirectional 2-layer LSTM ---------------------------
// 256 WGs x 256 thr, 1 WG/CU. grp = bi & 7 (one XCD per group under
// round-robin dispatch - perf heuristic; correctness via LLC bypass).
// Per step: stage X tile (fp16) + h tile (bf16 hi/lo, LLC-bypass) into LDS
// ONCE per WG, MFMA from LDS (XOR-swizzled, conflict-free), intra-wave shfl
// gate combine, distributed tag-mailbox sync.
__global__ __launch_bounds__(256, 1) void lstm_fused_kernel(
    const ushort* __restrict__ Xf,             // [T*64][1024] fp16 (layer-0 in)
    ushort* __restrict__ O0f,                  // [T*64][1024] fp16 (layer-0 out)
    const ushort* __restrict__ Wih16,          // [L*2*2048][1024] fp16
    const __hip_bfloat16* __restrict__ WhhHi,  // [L*2*2048][512] bf16 hi
    const __hip_bfloat16* __restrict__ WhhLo,  //                bf16 lo
    const float* __restrict__ b_ih, const float* __restrict__ b_hh,
    const int* __restrict__ mask,
    uint* __restrict__ Hpk,                    // [2 d][2 slot][64][512] bf16 hi|lo
    uint* __restrict__ tags,                   // [8 grp][32 WG] spaced 32 dwords
    uint* __restrict__ gcnt,
    float* __restrict__ out)
{
  extern __shared__ short lds[];
  short* XF = lds;          // 16 x 1024 fp16 (32 KB), granule-swizzled
  short* HH = lds + 16384;  // 16 x 512 bf16 hi (16 KB)
  short* HL = lds + 24576;  // 16 x 512 bf16 lo (16 KB)

  const int tid = threadIdx.x;
  const int w = tid >> 6, l = tid & 63;
  const int lane15 = l & 15, quad = l >> 4;
  const int gn = lane15 >> 2, jn = lane15 & 3;
  const int bi = blockIdx.x;
  const int grp = bi & 7, nc = bi >> 3;
  const int d = grp >> 2, ms = grp & 3;
  const int b0 = ms * 16, j0 = nc * 16;
  const int jcol = j0 + w * 4 + jn;
  const int row16 = tid >> 4, seg = tid & 15;   // staging decomposition
  uint* mytag = tags + grp * 1024 + nc * 32;
  const uint* grptags = tags + grp * 1024;

  uint gen = 0;

  for (int layer = 0; layer < 2; ++layer) {
    if (layer == 1) {   // one-time inter-layer rendezvous
      __builtin_amdgcn_s_waitcnt(0);
      __syncthreads();
      if (tid == 0) {
        __hip_atomic_fetch_add(gcnt, 1u, __ATOMIC_RELAXED, __HIP_MEMORY_SCOPE_AGENT);
        while (__hip_atomic_load(gcnt, __ATOMIC_RELAXED, __HIP_MEMORY_SCOPE_AGENT) < 256u)
          __builtin_amdgcn_s_sleep(4);
      }
      __syncthreads();
    }

    // ---- register-resident weights: wih (fp16), whh (bf16 hi+lo) ----
    const size_t rw = (size_t)((layer * 2 + d) * 2048 + gn * 512 + jcol);
    half8 wih[32];
    {
      const ushort* pw = Wih16 + rw * 1024 + quad * 8;
      #pragma unroll
      for (int kk = 0; kk < 32; ++kk) wih[kk] = *(const half8*)(pw + kk * 32);
    }
    short8 whh_h[16], whh_l[16];
    {
      const __hip_bfloat16* ph = WhhHi + rw * 512 + quad * 8;
      const __hip_bfloat16* pl = WhhLo + rw * 512 + quad * 8;
      #pragma unroll
      for (int kk = 0; kk < 16; ++kk) {
        whh_h[kk] = *(const short8*)(ph + kk * 32);
        whh_l[kk] = *(const short8*)(pl + kk * 32);
      }
    }
    float bias_c[4];
    #pragma unroll
    for (int g2 = 0; g2 < 4; ++g2) {
      int o = (layer * 2 + d) * 2048 + g2 * 512 + jcol;
      bias_c[g2] = b_ih[o] + b_hh[o];
    }
    const ushort* Xp = layer ? O0f : Xf;

    f32x4 c4 = {0.f, 0.f, 0.f, 0.f};

    // ---- init publish: h(slot 0) = 0 ----
    if (gn == 0) {
      #pragma unroll
      for (int r = 0; r < 4; ++r) {
        size_t ho = (((size_t)d * 2 + 0) * 64 + b0 + quad * 4 + r) * 512 + jcol;
        __hip_atomic_store(Hpk + ho, 0u, __ATOMIC_RELAXED, __HIP_MEMORY_SCOPE_AGENT);
      }
    }
    __builtin_amdgcn_s_waitcnt(0);
    __builtin_amdgcn_s_barrier();
    gen++;
    if (w == 0 && l == 0)
      __hip_atomic_store(mytag, gen, __ATOMIC_RELAXED, __HIP_MEMORY_SCOPE_AGENT);

    for (int s = 0; s < 256; ++s) {
      const int t = d ? (255 - s) : s;
      const int cur = s & 1, nxt = cur ^ 1;

      float mv[4];
      #pragma unroll
      for (int r = 0; r < 4; ++r) mv[r] = (float)mask[(b0 + quad * 4 + r) * 256 + t];

      // ---- A) stage X tile into LDS (fp16, plain cached, once per WG) ----
      {
        const ushort* xrow = Xp + (size_t)(t * 64 + b0 + row16) * 1024;
        #pragma unroll
        for (int gi = 0; gi < 8; ++gi) {
          int g = seg + gi * 16;                       // granule 0..127
          uint4 v = *(const uint4*)(xrow + g * 8);
          *(uint4*)(XF + row16 * 1024 + ((g ^ row16) & 127) * 8) = v;
        }
      }
      __syncthreads();

      // ---- B) x-projection MFMA from LDS (2 chains) ----
      f32x4 a0 = {}, a1 = {}, a2 = {}, a3 = {}, a4 = {};
      #pragma unroll
      for (int kk = 0; kk < 32; ++kk) {
        int o = lane15 * 1024 + (((kk * 4 + quad) ^ lane15) & 127) * 8;
        half8 xa = *(const half8*)(XF + o);
        if (kk & 1) a1 = MFMA_F16(xa, wih[kk], a1, 0, 0, 0);
        else        a0 = MFMA_F16(xa, wih[kk], a0, 0, 0, 0);
      }

      // ---- C) wait for h(cur): wave 0 polls 32 distributed tags ----
      if (w == 0) {
        for (;;) {
          uint v = 0xffffffffu;
          if (l < 32)
            v = __hip_atomic_load(grptags + l * 32, __ATOMIC_RELAXED, __HIP_MEMORY_SCOPE_AGENT);
          if (__all((int)(v >= gen))) break;
          __builtin_amdgcn_s_sleep(1);
        }
      }
      __atomic_signal_fence(__ATOMIC_ACQUIRE);
      __builtin_amdgcn_s_barrier();

      // ---- D) stage h tile into LDS (LLC-bypass, unpack bf16 hi/lo) ----
      {
        const uint* hrow = Hpk + (((size_t)d * 2 + cur) * 64 + b0 + row16) * 512;
        #pragma unroll
        for (int gi = 0; gi < 4; ++gi) {
          int g = seg + gi * 16;                       // granule 0..63
          const u64* p = (const u64*)(hrow + g * 8);
          u64 q0 = __hip_atomic_load(p + 0, __ATOMIC_RELAXED, __HIP_MEMORY_SCOPE_AGENT);
          u64 q1 = __hip_atomic_load(p + 1, __ATOMIC_RELAXED, __HIP_MEMORY_SCOPE_AGENT);
          u64 q2 = __hip_atomic_load(p + 2, __ATOMIC_RELAXED, __HIP_MEMORY_SCOPE_AGENT);
          u64 q3 = __hip_atomic_load(p + 3, __ATOMIC_RELAXED, __HIP_MEMORY_SCOPE_AGENT);
          uint vv[8];
          vv[0] = (uint)q0; vv[1] = (uint)(q0 >> 32); vv[2] = (uint)q1; vv[3] = (uint)(q1 >> 32);
          vv[4] = (uint)q2; vv[5] = (uint)(q2 >> 32); vv[6] = (uint)q3; vv[7] = (uint)(q3 >> 32);
          short8 hh8, hl8;
          #pragma unroll
          for (int e = 0; e < 8; ++e) { hh8[e] = (short)(vv[e] & 0xffffu); hl8[e] = (short)(vv[e] >> 16); }
          int o = row16 * 512 + ((g ^ row16) & 63) * 8;
          *(short8*)(HH + o) = hh8;
          *(short8*)(HL + o) = hl8;
        }
      }
      __syncthreads();

      // ---- E) recurrent MFMA from LDS (3 chains, bf16 3-term) ----
      #pragma unroll
      for (int kk = 0; kk < 16; ++kk) {
        int o = lane15 * 512 + (((kk * 4 + quad) ^ lane15) & 63) * 8;
        short8 hh = *(const short8*)(HH + o);
        short8 hl = *(const short8*)(HL + o);
        a2 = MFMA_BF16(hh, whh_h[kk], a2, 0, 0, 0);
        a3 = MFMA_BF16(hh, whh_l[kk], a3, 0, 0, 0);
        a4 = MFMA_BF16(hl, whh_h[kk], a4, 0, 0, 0);
      }
      f32x4 gsum = (a0 + a1) + (a2 + a3) + a4;

      // ---- F) gather 4 gates intra-wave, update, publish ----
      f32x4 p1v, p2v, p3v;
      #pragma unroll
      for (int e = 0; e < 4; ++e) {
        p1v[e] = __shfl_xor(gsum[e], 4);
        p2v[e] = __shfl_xor(gsum[e], 8);
        p3v[e] = __shfl_xor(gsum[e], 12);
      }
      f32x4 Gi = (gn == 0) ? gsum : (gn == 1) ? p1v : (gn == 2) ? p2v : p3v;
      f32x4 Gf = (gn == 0) ? p1v : (gn == 1) ? gsum : (gn == 2) ? p3v : p2v;
      f32x4 Gg = (gn == 0) ? p2v : (gn == 1) ? p3v : (gn == 2) ? gsum : p1v;
      f32x4 Go = (gn == 0) ? p3v : (gn == 1) ? p2v : (gn == 2) ? p1v : gsum;

      float hval[4];
      #pragma unroll
      for (int r = 0; r < 4; ++r) {
        float gi = Gi[r] + bias_c[0];
        float gf = Gf[r] + bias_c[1];
        float gg = Gg[r] + bias_c[2];
        float go = Go[r] + bias_c[3];
        float cn = sigf(gf) * c4[r] + sigf(gi) * tanh_fast(gg);
        float h  = sigf(go) * tanh_fast(cn);
        h *= mv[r]; cn *= mv[r];
        c4[r] = cn;
        hval[r] = h;
      }

      #pragma unroll
      for (int r = 0; r < 4; ++r) {
        // fp16 pair for O0 (lane jn even stores jcol,jcol+1 as one dword)
        uint myh = f2h16u(hval[r]);
        uint oth = (uint)__shfl_xor((int)myh, 1);
        if (gn == 0) {
          ushort uh = f2bfu(hval[r]);
          ushort ul = f2bfu(hval[r] - bfu2f(uh));
          uint pk = (uint)uh | ((uint)ul << 16);
          size_t ho = (((size_t)d * 2 + nxt) * 64 + b0 + quad * 4 + r) * 512 + jcol;
          __hip_atomic_store(Hpk + ho, pk, __ATOMIC_RELAXED, __HIP_MEMORY_SCOPE_AGENT);
          size_t oo = (size_t)(t * 64 + b0 + quad * 4 + r) * 1024 + d * 512 + jcol;
          if (layer == 0) {
            if (!(jn & 1))
              __hip_atomic_store((uint*)O0f + (oo >> 1), myh | (oth << 16),
                                 __ATOMIC_RELAXED, __HIP_MEMORY_SCOPE_AGENT);
          } else {
            out[oo] = hval[r];
          }
        }
      }
      __atomic_signal_fence(__ATOMIC_SEQ_CST);
      __builtin_amdgcn_s_waitcnt(0);      // publishes ACKed at LLC
      __builtin_amdgcn_s_barrier();       // whole WG drained
      gen++;
      if (w == 0 && l == 0)
        __hip_atomic_store(mytag, gen, __ATOMIC_RELAXED, __HIP_MEMORY_SCOPE_AGENT);
    }
  }
}

// ---- host ------------------------------------------------------------------
extern "C" void kernel_launch(void* const* d_in, const int* in_sizes, int n_in,
                              void* d_out, int out_size, void* d_ws, size_t ws_size,
                              hipStream_t stream) {
  const float* x    = (const float*)d_in[0];
  const int*   mask = (const int*)  d_in[1];
  const float* w_ih = (const float*)d_in[2];
  const float* w_hh = (const float*)d_in[3];
  const float* b_ih = (const float*)d_in[4];
  const float* b_hh = (const float*)d_in[5];
  float* outp = (float*)d_out;

  char* ws = (char*)d_ws;
  size_t off = 0;
  auto take = [&](size_t bytes) -> char* {
    char* p = ws + off;
    off += (bytes + 255) & ~(size_t)255;
    return p;
  };
  const size_t NX   = (size_t)T_SEQ * NB * KIN;      // 16.7M
  const size_t NWIH = (size_t)2 * 2 * 2048 * 1024;
  const size_t NWHH = (size_t)2 * 2 * 2048 * 512;
  const size_t NHP  = (size_t)2 * 2 * NB * HDIM;

  ushort*         Xf    = (ushort*)        take(NX * 2);     // 33.5 MB
  ushort*         O0f   = (ushort*)        take(NX * 2);     // 33.5 MB
  ushort*         Wih16 = (ushort*)        take(NWIH * 2);   // 16.8 MB
  __hip_bfloat16* WhhHi = (__hip_bfloat16*)take(NWHH * 2);
  __hip_bfloat16* WhhLo = (__hip_bfloat16*)take(NWHH * 2);
  uint*           Hpk   = (uint*)          take(NHP * 4);
  uint*           tags  = (uint*)          take(8 * 1024 * 4);
  uint*           gcnt  = (uint*)          take(256);

  hipMemsetAsync(tags, 0, 8 * 1024 * 4, stream);
  hipMemsetAsync(gcnt, 0, 256, stream);

  { int n = (int)NX;   conv_f16_kernel<<<(n + 255) / 256, 256, 0, stream>>>(x,    Xf,    n); }
  { int n = (int)NWIH; conv_f16_kernel<<<(n + 255) / 256, 256, 0, stream>>>(w_ih, Wih16, n); }
  { int n = (int)NWHH; split_kernel<<<(n + 255) / 256, 256, 0, stream>>>(w_hh, WhhHi, WhhLo, n); }

  lstm_fused_kernel<<<256, 256, 65536, stream>>>(
      Xf, O0f, Wih16, WhhHi, WhhLo, b_ih, b_hh, mask, Hpk, tags, gcnt, outp);
}